// Round 3
// baseline (951.296 us; speedup 1.0000x reference)
//
#include <hip/hip_runtime.h>

typedef float f4 __attribute__((ext_vector_type(4)));
typedef int i4 __attribute__((ext_vector_type(4)));
typedef __bf16 bf16x8 __attribute__((ext_vector_type(8)));
typedef unsigned short u16;

#define DEV static __device__ __forceinline__

DEV f4 mfma_bf16(bf16x8 a, bf16x8 b, f4 c) {
  return __builtin_amdgcn_mfma_f32_16x16x32_bf16(a, b, c, 0, 0, 0);
}

DEV bf16x8 ld_frag(const u16* p) {  // 16B LDS load -> bf16x8 fragment
  union { i4 i; bf16x8 b; } u;
  u.i = *(const i4*)p;
  return u.b;
}

DEV u16 f2bf(float f) {  // RNE f32 -> bf16 bits
  union { float f; unsigned int u; } v; v.f = f;
  return (u16)((v.u + 0x7fffu + ((v.u >> 16) & 1u)) >> 16);
}

// async global->LDS, 16B/lane; LDS dest is wave-uniform base + lane*16
DEV void async_cp16(const void* g, void* l) {
  __builtin_amdgcn_global_load_lds((const __attribute__((address_space(1))) void*)g,
                                   (__attribute__((address_space(3))) void*)l, 16, 0, 0);
}

// ---------- x: (B,C,THW) f32 -> xt: (B*THW, C) bf16 ----------
__global__ __launch_bounds__(256) void k_transpose_x(const float* __restrict__ x,
                                                     u16* __restrict__ xt) {
  __shared__ float tile[32][33];
  const int b = blockIdx.z;
  const int thw0 = blockIdx.x * 32;
  const int c0 = blockIdx.y * 32;
  const int tc = threadIdx.x & 31;
  const int tr = threadIdx.x >> 5;  // 0..7
#pragma unroll
  for (int i = 0; i < 4; i++) {
    int c = tr + i * 8;
    tile[c][tc] = x[(long)(b * 512 + c0 + c) * 16384 + thw0 + tc];
  }
  __syncthreads();
#pragma unroll
  for (int i = 0; i < 4; i++) {
    int r = tr + i * 8;
    xt[(long)(b * 16384 + thw0 + r) * 512 + c0 + tc] = f2bf(tile[tc][r]);
  }
}

// ---------- pack weights: Wqkv (4608,512) bf16, WoCat (512,1536) bf16, bo sum ----------
__global__ __launch_bounds__(256) void k_prep_w(
    const float* wq_w, const float* wk_w, const float* wv_w, const float* wo_w, const float* bo_w,
    const float* wq_h, const float* wk_h, const float* wv_h, const float* wo_h, const float* bo_h,
    const float* wq_t, const float* wk_t, const float* wv_t, const float* wo_t, const float* bo_t,
    u16* Wqkv, u16* WoCat, float* bo) {
  const int idx = blockIdx.x * 256 + threadIdx.x;
  if (idx < 2359296) {  // Wqkv row j = a*1536 + which*512 + co, col ci
    int j = idx >> 9, ci = idx & 511;
    int sel = j >> 9, co = j & 511;  // sel = a*3+which
    const float* s;
    switch (sel) {
      case 0: s = wq_w; break; case 1: s = wk_w; break; case 2: s = wv_w; break;
      case 3: s = wq_h; break; case 4: s = wk_h; break; case 5: s = wv_h; break;
      case 6: s = wq_t; break; case 7: s = wk_t; break; default: s = wv_t; break;
    }
    Wqkv[idx] = f2bf(s[co * 512 + ci]);
  } else if (idx < 2359296 + 786432) {  // WoCat[c][a*512+ci] = Wo_a[c][ci]
    int t = idx - 2359296;
    int c = t / 1536, j2 = t - c * 1536;
    int a = j2 >> 9, ci = j2 & 511;
    const float* s = (a == 0) ? wo_w : (a == 1) ? wo_h : wo_t;
    WoCat[t] = f2bf(s[c * 512 + ci]);
  } else if (idx < 2359296 + 786432 + 512) {
    int c = idx - (2359296 + 786432);
    bo[c] = bo_w[c] + bo_h[c] + bo_t[c];
  }
}

// ---------- 256x128 co-resident pipelined GEMM: C = A(MxK) * Bt(NxK)^T ----------
// BK=32, 8 waves x (64x64 output), acc=64 VGPR -> <=128 VGPR/wave -> 2 blocks/CU
// (16 waves). LDS: 2 x 24 KiB staging bufs (+epilogue) = 72 KiB -> 2 blocks fit.
// Counted-vmcnt pipeline (per K-tile t):
//   LD frags(t) from buf[t&1]; lgkmcnt(0); BAR   // reads retired -> buf free
//   STAGE(t+2 -> buf[t&1])                        // 3 cp16/thread
//   MFMA x16 (setprio-wrapped)
//   WAITV(3)  // t+1 landed; t+2's 3 stay in flight (never drain to 0)
//   BAR       // publish buf[(t+1)&1]
// Co-residency de-serializes LDS-read vs MFMA phases across the two blocks.
// Swizzle (64-B rows = 4 chunks): store global chunk c of row r at phys
// p = c ^ ((r>>1)&3). Fragment reads then hit phys p = q ^ ((cl>>1)&3):
// per quarter-wave each (4-bank group, row-parity) gets exactly 2 lanes (free).
// Inverse perm on per-lane GLOBAL source; LDS dest linear (m173 rule).
template <int NK, int EPI, int NT, int MT, bool MMINOR>
__global__ __launch_bounds__(512, 4) void k_gemm(
    const u16* __restrict__ A, const u16* __restrict__ Bt,
    void* __restrict__ Co, const float* __restrict__ bias, int ldc) {
  constexpr int K = NK * 32;  // NK = # of 32-wide K-tiles
  __shared__ __attribute__((aligned(16))) u16 lds[36864];  // 72 KiB
  // buf b (=t&1) at b*12288 u16: A [256 rows][4 chunks] (8192 u16), B at +8192.

  const int tid = threadIdx.x;
  const int lane = tid & 63, wave = tid >> 6;
  const int cl = lane & 15, q = lane >> 4;
  const int wr = wave >> 1, wc = wave & 1;  // 4 x 2 wave grid of 64x64 tiles

  // XCD-aware chunked block swizzle (bijective: NT*MT % 8 == 0)
  const int bid = blockIdx.x;
  const int orig = (bid & 7) * ((NT * MT) >> 3) + (bid >> 3);
  const int my = MMINOR ? (orig % MT) : (orig / NT);
  const int nx = MMINOR ? (orig / MT) : (orig % NT);
  const long m0 = (long)my * 256;
  const long n0 = (long)nx * 128;
  const u16* Ab = A + m0 * K;
  const u16* Bb = Bt + n0 * K;

  // staging: A tile 256x32 = 1024 chunks (2/thread), B tile 128x32 = 512 (1/thread)
  // slot s=(row,p): receives global chunk c = p ^ ((row>>1)&3)
  int goffA0, goffA1, goffB, dA0, dA1, dB;
  {
    int s0 = tid, r0 = s0 >> 2, c0 = (s0 & 3) ^ ((r0 >> 1) & 3);
    goffA0 = r0 * K + c0 * 8;
    int s1 = 512 + tid, r1 = s1 >> 2, c1 = (s1 & 3) ^ ((r1 >> 1) & 3);
    goffA1 = r1 * K + c1 * 8;
    goffB = goffA0;  // same geometry for B rows 0..127
    dA0 = (tid & 448) * 8;          // wave-uniform dest (u16 units)
    dA1 = (512 + (tid & 448)) * 8;
    dB = (tid & 448) * 8;
  }

#define STG(t)                                                         \
  {                                                                    \
    u16* lb_ = lds + ((t) & 1) * 12288;                                \
    async_cp16(Ab + goffA0 + (t) * 32, lb_ + dA0);                     \
    async_cp16(Ab + goffA1 + (t) * 32, lb_ + dA1);                     \
    async_cp16(Bb + goffB + (t) * 32, lb_ + 8192 + dB);                \
  }
#define BAR() __builtin_amdgcn_s_barrier()
#define WAITV(N) asm volatile("s_waitcnt vmcnt(" #N ")" ::: "memory")
#define WAITL() asm volatile("s_waitcnt lgkmcnt(0)" ::: "memory")

  // fragment read: phys chunk offset constant per lane
  const int pOff = (q ^ ((cl >> 1) & 3)) * 8;
  const int arow = (wr * 64 + cl) * 32 + pOff;
  const int brow = (wc * 64 + cl) * 32 + pOff;

  f4 acc[4][4];
  {
    f4 z; z[0] = z[1] = z[2] = z[3] = 0.f;
#pragma unroll
    for (int m = 0; m < 4; m++)
#pragma unroll
      for (int n = 0; n < 4; n++) acc[m][n] = z;
  }

  // prologue: stage tiles 0,1; wait tile 0 (tile 1's 3 loads stay in flight)
  STG(0);
  STG(1);
  WAITV(3);
  BAR();

#pragma unroll 1
  for (int t = 0; t < NK; ++t) {
    const u16* base = lds + (t & 1) * 12288;
    bf16x8 af[4], bf[4];
#pragma unroll
    for (int m = 0; m < 4; m++) af[m] = ld_frag(base + arow + m * 512);
#pragma unroll
    for (int n = 0; n < 4; n++) bf[n] = ld_frag(base + 8192 + brow + n * 512);
    WAITL();   // frags in regs -> buf[t&1] reusable after barrier
    BAR();
    if (t + 2 < NK) STG(t + 2);
    __builtin_amdgcn_s_setprio(1);
#pragma unroll
    for (int m = 0; m < 4; m++)
#pragma unroll
      for (int n = 0; n < 4; n++)
        acc[m][n] = mfma_bf16(af[m], bf[n], acc[m][n]);
    __builtin_amdgcn_s_setprio(0);
    if (t + 2 < NK) WAITV(3);        // t+1 landed, t+2 in flight
    else if (t + 1 < NK) WAITV(0);   // last prefetch: full drain once
    BAR();
  }
#undef STG
#undef BAR
#undef WAITV
#undef WAITL

  if (EPI == 0) {
    // bf16 row-major epilogue: per-wave LDS repack -> coalesced 16B stores
    u16* myl = lds + wave * 4608;  // 64 rows x 72 u16 per wave
    u16* CoB = (u16*)Co;
#pragma unroll
    for (int m = 0; m < 4; m++)
#pragma unroll
      for (int n = 0; n < 4; n++)
#pragma unroll
        for (int r = 0; r < 4; r++)
          myl[(m * 16 + q * 4 + r) * 72 + n * 16 + cl] = f2bf(acc[m][n][r]);
#pragma unroll
    for (int it = 0; it < 8; it++) {
      int lr = it * 8 + (lane >> 3);
      int lc = (lane & 7) * 8;
      i4 v = *(const i4*)(myl + lr * 72 + lc);
      *(i4*)(CoB + (m0 + wr * 64 + lr) * ldc + n0 + wc * 64 + lc) = v;
    }
  } else {
    // fp32 scatter epilogue (final GEMM): rows are channels, cols are tokens
    float* Cf = (float*)Co;
#pragma unroll
    for (int m = 0; m < 4; m++)
#pragma unroll
      for (int r = 0; r < 4; r++) {
        int c = (int)m0 + wr * 64 + m * 16 + q * 4 + r;
        float bv = bias[c];
#pragma unroll
        for (int n = 0; n < 4; n++) {
          long nn = n0 + wc * 64 + n * 16 + cl;  // token
          long b = nn >> 14, thw = nn & 16383;
          Cf[((b * 512 + c) << 14) + thw] = acc[m][n][r] + bv;
        }
      }
  }
}

// ---------- axial attention: 1 wave per (group, head), MFMA QK^T and PV ----------
template <int L>
__global__ __launch_bounds__(64) void k_attn(
    const u16* __restrict__ QKV, u16* __restrict__ Oc,
    int inner, int istride, int ostride, int obase, int tstride) {
  constexpr int NT = L / 16;
  __shared__ __attribute__((aligned(16))) u16 sQ[2048];   // 32x64
  __shared__ __attribute__((aligned(16))) u16 sK[2048];   // 32x64
  __shared__ __attribute__((aligned(16))) u16 sVt[2560];  // 64ch x 40 (32 tok + pad)
  __shared__ __attribute__((aligned(16))) u16 sPbuf[(L == 16) ? 1280 : 1];
  u16* sP = (L == 16) ? sPbuf : sQ;  // L=32: sQ is dead after QK^T; alias saves LDS
  const int lane = threadIdx.x;
  const int cl = lane & 15, q = lane >> 4;
  const int g = blockIdx.x, head = blockIdx.y;
  const long tok0 = (long)(g / inner) * ostride + (long)(g % inner) * istride;
  const long rs = (long)tstride * 1536;
  const u16* qb = QKV + tok0 * 1536 + head * 64;
  const u16* kb = qb + 512;
  const u16* vb = qb + 1024;

  if (L == 16) {  // zero K-dim padding (cols 16..31 of P and Vt must be 0)
    unsigned int* z1 = (unsigned int*)sVt;
    for (int i = lane; i < 1280; i += 64) z1[i] = 0;
    unsigned int* z2 = (unsigned int*)sPbuf;
    for (int i = lane; i < 640; i += 64) z2[i] = 0;
  }

#pragma unroll
  for (int i = 0; i < L / 8; i++) {  // Q,K swizzled async stage
    int s = i * 64 + lane;
    int row = s >> 3;
    int gc = (s & 7) ^ (row & 7);
    async_cp16(qb + row * rs + gc * 8, (char*)sQ + i * 1024);
    async_cp16(kb + row * rs + gc * 8, (char*)sK + i * 1024);
  }
#pragma unroll
  for (int i = 0; i < L / 8; i++) {  // V load + transpose into sVt[ch][tok]
    int s = i * 64 + lane;
    int row = s >> 3, c8 = s & 7;
    union { i4 v; u16 h[8]; } raw;
    raw.v = *(const i4*)(vb + row * rs + c8 * 8);
#pragma unroll
    for (int j = 0; j < 8; j++) sVt[(c8 * 8 + j) * 40 + row] = raw.h[j];
  }
  __syncthreads();

  // S = Q K^T
  f4 sacc[NT][NT];
  { f4 z; z[0]=z[1]=z[2]=z[3]=0.f;
    for (int a = 0; a < NT; a++) for (int b2 = 0; b2 < NT; b2++) sacc[a][b2] = z; }
#pragma unroll
  for (int kk = 0; kk < 2; kk++) {
    bf16x8 qf[NT], kf[NT];
#pragma unroll
    for (int t = 0; t < NT; t++) {
      int row = t * 16 + cl;
      int ch = (kk * 4 + q) ^ (row & 7);
      qf[t] = ld_frag(sQ + row * 64 + ch * 8);
      kf[t] = ld_frag(sK + row * 64 + ch * 8);
    }
#pragma unroll
    for (int rt = 0; rt < NT; rt++)
#pragma unroll
      for (int ct = 0; ct < NT; ct++)
        sacc[rt][ct] = mfma_bf16(qf[rt], kf[ct], sacc[rt][ct]);
  }

  // softmax over keys; C-layout: row = q*4+i (+16*rt), col = cl (+16*ct)
#pragma unroll
  for (int rt = 0; rt < NT; rt++)
#pragma unroll
    for (int ct = 0; ct < NT; ct++)
#pragma unroll
      for (int i = 0; i < 4; i++) sacc[rt][ct][i] *= 0.125f;  // 1/sqrt(64)
#pragma unroll
  for (int rt = 0; rt < NT; rt++)
#pragma unroll
    for (int i = 0; i < 4; i++) {
      float m = sacc[rt][0][i];
#pragma unroll
      for (int ct = 1; ct < NT; ct++) m = fmaxf(m, sacc[rt][ct][i]);
      for (int off = 1; off < 16; off <<= 1) m = fmaxf(m, __shfl_xor(m, off, 64));
      float ssum = 0.f;
#pragma unroll
      for (int ct = 0; ct < NT; ct++) {
        float p = __expf(sacc[rt][ct][i] - m);
        sacc[rt][ct][i] = p;
        ssum += p;
      }
      for (int off = 1; off < 16; off <<= 1) ssum += __shfl_xor(ssum, off, 64);
      float inv = 1.0f / ssum;
#pragma unroll
      for (int ct = 0; ct < NT; ct++) sacc[rt][ct][i] *= inv;
    }

  // P -> LDS (A-operand layout source)
#pragma unroll
  for (int rt = 0; rt < NT; rt++)
#pragma unroll
    for (int ct = 0; ct < NT; ct++)
#pragma unroll
      for (int i = 0; i < 4; i++)
        sP[(rt * 16 + q * 4 + i) * 40 + ct * 16 + cl] = f2bf(sacc[rt][ct][i]);
  __syncthreads();

  // O = P V  (K=32, padded with zeros when L=16)
  bf16x8 pf[NT], vf[4];
#pragma unroll
  for (int mt = 0; mt < NT; mt++) pf[mt] = ld_frag(sP + (mt * 16 + cl) * 40 + q * 8);
#pragma unroll
  for (int nt = 0; nt < 4; nt++) vf[nt] = ld_frag(sVt + (nt * 16 + cl) * 40 + q * 8);
  f4 oacc[NT][4];
  { f4 z; z[0]=z[1]=z[2]=z[3]=0.f;
    for (int a = 0; a < NT; a++) for (int b2 = 0; b2 < 4; b2++) oacc[a][b2] = z; }
#pragma unroll
  for (int mt = 0; mt < NT; mt++)
#pragma unroll
    for (int nt = 0; nt < 4; nt++)
      oacc[mt][nt] = mfma_bf16(pf[mt], vf[nt], oacc[mt][nt]);

#pragma unroll
  for (int mt = 0; mt < NT; mt++)
#pragma unroll
    for (int i = 0; i < 4; i++) {
      int r = mt * 16 + q * 4 + i;  // token within group
      u16* dst = Oc + (tok0 + (long)r * tstride) * 1536 + obase + head * 64;
#pragma unroll
      for (int nt = 0; nt < 4; nt++) dst[nt * 16 + cl] = f2bf(oacc[mt][nt][i]);
    }
}

extern "C" void kernel_launch(void* const* d_in, const int* in_sizes, int n_in,
                              void* d_out, int out_size, void* d_ws, size_t ws_size,
                              hipStream_t stream) {
  (void)in_sizes; (void)n_in; (void)out_size; (void)ws_size;
  const float* x    = (const float*)d_in[0];
  const float* wq_w = (const float*)d_in[1];
  const float* wk_w = (const float*)d_in[2];
  const float* wv_w = (const float*)d_in[3];
  const float* wo_w = (const float*)d_in[4];
  const float* bo_w = (const float*)d_in[5];
  const float* wq_h = (const float*)d_in[6];
  const float* wk_h = (const float*)d_in[7];
  const float* wv_h = (const float*)d_in[8];
  const float* wo_h = (const float*)d_in[9];
  const float* bo_h = (const float*)d_in[10];
  const float* wq_t = (const float*)d_in[11];
  const float* wk_t = (const float*)d_in[12];
  const float* wv_t = (const float*)d_in[13];
  const float* wo_t = (const float*)d_in[14];
  const float* bo_t = (const float*)d_in[15];

  char* ws = (char*)d_ws;
  u16* xt    = (u16*)(ws);                 //  64 MiB  (65536 x 512 bf16)
  u16* qkv   = (u16*)(ws + 67108864L);     // 192 MiB  (65536 x 1536 bf16, per-branch)
  u16* oc    = (u16*)(ws + 268435456L);    // 192 MiB  (65536 x 1536 bf16 concat)
  u16* Wqkv  = (u16*)(ws + 469762048L);    // 4.5 MiB
  u16* WoCat = (u16*)(ws + 474480640L);    // 1.5 MiB
  float* bo  = (float*)(ws + 476053504L);  // 2 KiB

  k_transpose_x<<<dim3(512, 16, 4), 256, 0, stream>>>(x, xt);
  k_prep_w<<<dim3(12290), 256, 0, stream>>>(wq_w, wk_w, wv_w, wo_w, bo_w,
                                            wq_h, wk_h, wv_h, wo_h, bo_h,
                                            wq_t, wk_t, wv_t, wo_t, bo_t,
                                            Wqkv, WoCat, bo);
  for (int a = 0; a < 3; a++) {
    // QKV projection for branch a: (65536x512) @ (1536x512)^T -> (65536x1536) bf16
    // NK=16 (K=512), NT=12 n-tiles, MT=256 m-tiles, m-major (A-panel L2 reuse)
    k_gemm<16, 0, 12, 256, false><<<dim3(3072), 512, 0, stream>>>(
        xt, Wqkv + (long)a * 1536 * 512, qkv, nullptr, 1536);
    if (a == 0)        // width:  tok0 = g*32, stride 1
      k_attn<32><<<dim3(2048, 8), 64, 0, stream>>>(qkv, oc, 1, 0, 32, 0, 1);
    else if (a == 1)   // height: tok0 = (g/32)*1024 + g%32, stride 32
      k_attn<32><<<dim3(2048, 8), 64, 0, stream>>>(qkv, oc, 32, 1, 1024, 512, 32);
    else               // time:   tok0 = (g/1024)*16384 + g%1024, stride 1024, L=16
      k_attn<16><<<dim3(4096, 8), 64, 0, stream>>>(qkv, oc, 1024, 1, 16384, 1024, 1024);
  }
  // Out^T = WoCat(512x1536) @ oc(65536x1536)^T, +bias, scatter to (B,C,T,H,W) f32
  // NK=48 (K=1536), NT=512 n-tiles, MT=2 m-tiles, m-minor (oc L2 pairing)
  k_gemm<48, 1, 512, 2, true><<<dim3(1024), 512, 0, stream>>>(
      WoCat, oc, (float*)d_out, bo, 0);
}

// Round 4
// 894.875 us; speedup vs baseline: 1.0630x; 1.0630x over previous
//
#include <hip/hip_runtime.h>

typedef float f4 __attribute__((ext_vector_type(4)));
typedef int i4 __attribute__((ext_vector_type(4)));
typedef __bf16 bf16x8 __attribute__((ext_vector_type(8)));
typedef unsigned short u16;

#define DEV static __device__ __forceinline__

DEV f4 mfma_bf16(bf16x8 a, bf16x8 b, f4 c) {
  return __builtin_amdgcn_mfma_f32_16x16x32_bf16(a, b, c, 0, 0, 0);
}

DEV bf16x8 ld_frag(const u16* p) {  // 16B load -> bf16x8 fragment
  union { i4 i; bf16x8 b; } u;
  u.i = *(const i4*)p;
  return u.b;
}

DEV u16 f2bf(float f) {  // RNE f32 -> bf16 bits
  union { float f; unsigned int u; } v; v.f = f;
  return (u16)((v.u + 0x7fffu + ((v.u >> 16) & 1u)) >> 16);
}

// async global->LDS, 16B/lane; LDS dest is wave-uniform base + lane*16
DEV void async_cp16(const void* g, void* l) {
  __builtin_amdgcn_global_load_lds((const __attribute__((address_space(1))) void*)g,
                                   (__attribute__((address_space(3))) void*)l, 16, 0, 0);
}

// ---------- x: (B,C,THW) f32 -> xt: (B*THW, C) bf16 ----------
__global__ __launch_bounds__(256) void k_transpose_x(const float* __restrict__ x,
                                                     u16* __restrict__ xt) {
  __shared__ float tile[32][33];
  const int b = blockIdx.z;
  const int thw0 = blockIdx.x * 32;
  const int c0 = blockIdx.y * 32;
  const int tc = threadIdx.x & 31;
  const int tr = threadIdx.x >> 5;  // 0..7
#pragma unroll
  for (int i = 0; i < 4; i++) {
    int c = tr + i * 8;
    tile[c][tc] = x[(long)(b * 512 + c0 + c) * 16384 + thw0 + tc];
  }
  __syncthreads();
#pragma unroll
  for (int i = 0; i < 4; i++) {
    int r = tr + i * 8;
    xt[(long)(b * 16384 + thw0 + r) * 512 + c0 + tc] = f2bf(tile[tc][r]);
  }
}

// ---------- pack weights: Wqkv (4608,512) bf16, WoCat (512,1536) bf16, bo sum ----------
__global__ __launch_bounds__(256) void k_prep_w(
    const float* wq_w, const float* wk_w, const float* wv_w, const float* wo_w, const float* bo_w,
    const float* wq_h, const float* wk_h, const float* wv_h, const float* wo_h, const float* bo_h,
    const float* wq_t, const float* wk_t, const float* wv_t, const float* wo_t, const float* bo_t,
    u16* Wqkv, u16* WoCat, float* bo) {
  const int idx = blockIdx.x * 256 + threadIdx.x;
  if (idx < 2359296) {  // Wqkv row j = a*1536 + which*512 + co, col ci
    int j = idx >> 9, ci = idx & 511;
    int sel = j >> 9, co = j & 511;  // sel = a*3+which
    const float* s;
    switch (sel) {
      case 0: s = wq_w; break; case 1: s = wk_w; break; case 2: s = wv_w; break;
      case 3: s = wq_h; break; case 4: s = wk_h; break; case 5: s = wv_h; break;
      case 6: s = wq_t; break; case 7: s = wk_t; break; default: s = wv_t; break;
    }
    Wqkv[idx] = f2bf(s[co * 512 + ci]);
  } else if (idx < 2359296 + 786432) {  // WoCat[c][a*512+ci] = Wo_a[c][ci]
    int t = idx - 2359296;
    int c = t / 1536, j2 = t - c * 1536;
    int a = j2 >> 9, ci = j2 & 511;
    const float* s = (a == 0) ? wo_w : (a == 1) ? wo_h : wo_t;
    WoCat[t] = f2bf(s[c * 512 + ci]);
  } else if (idx < 2359296 + 786432 + 512) {
    int c = idx - (2359296 + 786432);
    bo[c] = bo_w[c] + bo_h[c] + bo_t[c];
  }
}

// ---------- 256x256 8-phase GEMM (m201 template): C = A(MxK) * Bt(NxK)^T ----------
// BK=64, 2 K-tiles/iteration, double-buffered 128 KiB LDS. Per phase:
// {ds-load reg subtile; stage one 16KiB half-tile; barrier; setprio1; 16 MFMA;
//  setprio0; barrier}. vmcnt(4) ONLY at phases 4 and 8 (2 half-tiles stay in
// flight; never drained in the main loop). Known-good config (round 2:
// QKV 131 us, MfmaUtil 33%, conflicts 786K).
template <int NK, int EPI, int NT, int MT, bool MMINOR>
__global__ __launch_bounds__(512, 2) void k_gemm256(
    const u16* __restrict__ A, const u16* __restrict__ Bt,
    void* __restrict__ Co, const float* __restrict__ bias, int ldc) {
  constexpr int K = NK * 64;   // NK = # of 64-wide K-tiles (even)
  constexpr int NIT = NK / 2;  // iterations, 2 K-tiles each
  __shared__ __attribute__((aligned(16))) u16 lds[65536];  // 128 KiB
  // buffer b(=ktile&1): A at b*32768 (256 rows x 64), B at b*32768+16384.

  const int tid = threadIdx.x;
  const int lane = tid & 63, wave = tid >> 6;
  const int cl = lane & 15, q = lane >> 4;
  const int wr = wave >> 2, wc = wave & 3;  // 2 x 4 wave grid

  // XCD-aware chunked block swizzle (bijective: NT*MT % 8 == 0)
  const int bid = blockIdx.x;
  const int orig = (bid & 7) * ((NT * MT) >> 3) + (bid >> 3);
  const int my = MMINOR ? (orig % MT) : (orig / NT);
  const int nx = MMINOR ? (orig / MT) : (orig % NT);
  const long m0 = (long)my * 256;
  const long n0 = (long)nx * 256;
  const u16* Ab = A + m0 * K;
  const u16* Bb = Bt + n0 * K;

  // staging precompute: half-tile = 128 rows x 64 u16 = 1024 16B chunks;
  // thread handles slots s = i*512+tid; slot (row, p=s&7) <- global chunk p^(row&7)
  long goff[2];
  int sdst[2];
#pragma unroll
  for (int i = 0; i < 2; i++) {
    int s = i * 512 + tid;
    int row = s >> 3;
    int c = (s & 7) ^ (row & 7);
    goff[i] = (long)row * K + c * 8;
    sdst[i] = (i * 512 + (tid & 448)) * 8;  // wave-uniform dest (u16 units)
  }

#define STG(op, h, t)                                                        \
  {                                                                          \
    const u16* gb_ = (op) ? Bb : Ab;                                         \
    u16* lb_ = lds + ((t) & 1) * 32768 + (op) * 16384 + (h) * 8192;          \
    _Pragma("unroll")                                                        \
    for (int i_ = 0; i_ < 2; i_++)                                           \
      async_cp16(gb_ + goff[i_] + (long)(h) * 128 * K + (t) * 64,            \
                 lb_ + sdst[i_]);                                            \
  }
#define BAR() __builtin_amdgcn_s_barrier()
#define WAITV(N) asm volatile("s_waitcnt vmcnt(" #N ")" ::: "memory")

  // fragment read addressing: phys chunk p = (ks*4+q) ^ (cl&7)
  const int pk0 = (q ^ (cl & 7)) * 8;
  const int pk1 = ((q + 4) ^ (cl & 7)) * 8;
  const int arow = (wr * 128 + cl) * 64;
  const int brow = (wc * 64 + cl) * 64;

  bf16x8 a[4][2], bl[2][2], bh[2][2];

#define LD_A(bb, mh)                                                         \
  _Pragma("unroll")                                                          \
  for (int m_ = 0; m_ < 4; m_++) {                                           \
    const u16* p_ = lds + (bb) * 32768 + arow + (mh) * 4096 + m_ * 1024;     \
    a[m_][0] = ld_frag(p_ + pk0);                                            \
    a[m_][1] = ld_frag(p_ + pk1);                                            \
  }
#define LD_BL(bb)                                                            \
  _Pragma("unroll")                                                          \
  for (int n_ = 0; n_ < 2; n_++) {                                           \
    const u16* p_ = lds + (bb) * 32768 + 16384 + brow + n_ * 1024;           \
    bl[n_][0] = ld_frag(p_ + pk0);                                           \
    bl[n_][1] = ld_frag(p_ + pk1);                                           \
  }
#define LD_BH(bb)                                                            \
  _Pragma("unroll")                                                          \
  for (int n_ = 0; n_ < 2; n_++) {                                           \
    const u16* p_ = lds + (bb) * 32768 + 16384 + brow + 2048 + n_ * 1024;    \
    bh[n_][0] = ld_frag(p_ + pk0);                                           \
    bh[n_][1] = ld_frag(p_ + pk1);                                           \
  }
#define MM(mh, nh, B)                                                        \
  __builtin_amdgcn_s_setprio(1);                                             \
  _Pragma("unroll")                                                          \
  for (int m_ = 0; m_ < 4; m_++)                                             \
    _Pragma("unroll")                                                        \
    for (int n_ = 0; n_ < 2; n_++)                                           \
      _Pragma("unroll")                                                      \
      for (int ks_ = 0; ks_ < 2; ks_++)                                      \
        acc[(mh) * 4 + m_][(nh) * 2 + n_] =                                  \
            mfma_bf16(a[m_][ks_], B[n_][ks_], acc[(mh) * 4 + m_][(nh) * 2 + n_]); \
  __builtin_amdgcn_s_setprio(0);

  f4 acc[8][4];
  {
    f4 z; z[0] = z[1] = z[2] = z[3] = 0.f;
#pragma unroll
    for (int m = 0; m < 8; m++)
#pragma unroll
      for (int n = 0; n < 4; n++) acc[m][n] = z;
  }

  // prologue: T0 fully + T1.B ; vmcnt(4) leaves T1.B in flight, T0 landed
  STG(1, 0, 0); STG(1, 1, 0); STG(0, 0, 0); STG(0, 1, 0);
  STG(1, 0, 1); STG(1, 1, 1);
  WAITV(4);
  BAR();

#define ITER_BODY(t, MORE)                                                   \
  /* K-tile t in buf0: phases 1-4 */                                         \
  LD_A(0, 0); LD_BL(0); STG(0, 0, (t) + 1);                                  \
  BAR(); MM(0, 0, bl); BAR();                                                \
  LD_BH(0); STG(0, 1, (t) + 1);                                              \
  BAR(); MM(0, 1, bh); BAR();                                                \
  LD_A(0, 1); if (MORE) STG(1, 0, (t) + 2);                                  \
  BAR(); MM(1, 0, bl); BAR();                                                \
  if (MORE) { STG(1, 1, (t) + 2); WAITV(4); } else { WAITV(0); }             \
  BAR(); MM(1, 1, bh); BAR();                                                \
  /* K-tile t+1 in buf1: phases 5-8 */                                       \
  LD_A(1, 0); LD_BL(1); if (MORE) STG(0, 0, (t) + 2);                        \
  BAR(); MM(0, 0, bl); BAR();                                                \
  LD_BH(1); if (MORE) STG(0, 1, (t) + 2);                                    \
  BAR(); MM(0, 1, bh); BAR();                                                \
  LD_A(1, 1); if (MORE) STG(1, 0, (t) + 3);                                  \
  BAR(); MM(1, 0, bl); BAR();                                                \
  if (MORE) { STG(1, 1, (t) + 3); WAITV(4); } else { WAITV(0); }             \
  BAR(); MM(1, 1, bh); BAR();

#pragma unroll 1
  for (int it = 0; it < NIT - 1; ++it) {
    const int t = 2 * it;
    ITER_BODY(t, true)
  }
  {
    const int t = 2 * (NIT - 1);
    ITER_BODY(t, false)
  }
#undef ITER_BODY
#undef MM
#undef LD_A
#undef LD_BL
#undef LD_BH
#undef STG
#undef WAITV
#undef BAR

  if (EPI == 0) {
    // bf16 row-major epilogue: per-wave LDS repack -> coalesced 16B stores
    __syncthreads();
    u16* myl = lds + wave * 4608;  // 64 rows x 72 u16 per wave (72 KiB total)
    u16* CoB = (u16*)Co;
#pragma unroll
    for (int h = 0; h < 2; h++) {
      if (h) __syncthreads();  // drain wave's h=0 LDS reads before rewriting
#pragma unroll
      for (int m = 0; m < 4; m++)
#pragma unroll
        for (int n = 0; n < 4; n++)
#pragma unroll
          for (int r = 0; r < 4; r++)
            myl[(m * 16 + q * 4 + r) * 72 + n * 16 + cl] = f2bf(acc[h * 4 + m][n][r]);
#pragma unroll
      for (int it = 0; it < 8; it++) {
        int lr = it * 8 + (lane >> 3);
        int lc = (lane & 7) * 8;
        i4 v = *(const i4*)(myl + lr * 72 + lc);
        *(i4*)(CoB + (m0 + wr * 128 + h * 64 + lr) * ldc + n0 + wc * 64 + lc) = v;
      }
    }
  } else {
    // fp32 scatter epilogue (final GEMM): rows are channels, cols are tokens
    float* Cf = (float*)Co;
#pragma unroll
    for (int m = 0; m < 8; m++)
#pragma unroll
      for (int r = 0; r < 4; r++) {
        int c = (int)m0 + wr * 128 + m * 16 + q * 4 + r;
        float bv = bias[c];
#pragma unroll
        for (int n = 0; n < 4; n++) {
          long nn = n0 + wc * 64 + n * 16 + cl;  // token
          long b = nn >> 14, thw = nn & 16383;
          Cf[((b * 512 + c) << 14) + thw] = acc[m][n][r] + bv;
        }
      }
  }
}

// ---------- axial attention v2: direct-register fragments, no barriers ----------
// 4 waves/block = 4 heads of one group. Q,K loaded straight from global into
// MFMA lane positions (16B/lane, 64B-contiguous per token row). V^T fragments
// via per-lane 2B loads (32B-coalesced segments; full V row consumed across nt).
// Only sP (P bounce, private per wave) lives in LDS -> no s_barrier anywhere,
// no V transpose, no staging conflicts. Occupancy ~4 waves/SIMD (VGPR-bound).
template <int L>
__global__ __launch_bounds__(256) void k_attn(
    const u16* __restrict__ QKV, u16* __restrict__ Oc,
    int inner, int istride, int ostride, int obase, int tstride) {
  constexpr int NT = L / 16;
  constexpr int PR = (L == 32) ? 40 : 24;           // sP row stride (u16), 16B-aligned reads
  constexpr int PSZ = (L == 32) ? 32 * 40 : 16 * 24; // per-wave sP size
  __shared__ __attribute__((aligned(16))) u16 sPall[4 * PSZ];
  const int tid = threadIdx.x;
  const int lane = tid & 63, wave = tid >> 6;
  u16* sP = sPall + wave * PSZ;
  const int cl = lane & 15, q = lane >> 4;
  const int g = blockIdx.x;
  const int head = blockIdx.y * 4 + wave;
  const long tok0 = (long)(g / inner) * ostride + (long)(g % inner) * istride;
  const long rs = (long)tstride * 1536;
  const u16* qb = QKV + tok0 * 1536 + head * 64;
  const u16* kb = qb + 512;
  const u16* vb = qb + 1024;

  // Q,K fragments: lane (cl,q) of frag (t,kk) = rows t*16+cl, k = (kk*4+q)*8..+7
  bf16x8 qf[NT][2], kf[NT][2];
#pragma unroll
  for (int t = 0; t < NT; t++)
#pragma unroll
    for (int kk = 0; kk < 2; kk++) {
      const long ro = (long)(t * 16 + cl) * rs + kk * 32 + q * 8;
      qf[t][kk] = ld_frag(qb + ro);
      kf[t][kk] = ld_frag(kb + ro);
    }

  // V^T fragments: vf[nt] elem j = V[q*8+j][nt*16+cl]; L=16: toks>=16 are zero
  bf16x8 vf[4];
#pragma unroll
  for (int nt = 0; nt < 4; nt++) {
    union { bf16x8 v; u16 h[8]; } u;
#pragma unroll
    for (int j = 0; j < 8; j++) {
      if (L == 32 || q < 2)
        u.h[j] = vb[(long)(q * 8 + j) * rs + nt * 16 + cl];
      else
        u.h[j] = 0;
    }
    vf[nt] = u.v;
  }

  // S = Q K^T
  f4 sacc[NT][NT];
  { f4 z; z[0]=z[1]=z[2]=z[3]=0.f;
    for (int a = 0; a < NT; a++) for (int b2 = 0; b2 < NT; b2++) sacc[a][b2] = z; }
#pragma unroll
  for (int kk = 0; kk < 2; kk++)
#pragma unroll
    for (int rt = 0; rt < NT; rt++)
#pragma unroll
      for (int ct = 0; ct < NT; ct++)
        sacc[rt][ct] = mfma_bf16(qf[rt][kk], kf[ct][kk], sacc[rt][ct]);

  // softmax over keys; C-layout: row = q*4+i (+16*rt), col = cl (+16*ct)
#pragma unroll
  for (int rt = 0; rt < NT; rt++)
#pragma unroll
    for (int ct = 0; ct < NT; ct++)
#pragma unroll
      for (int i = 0; i < 4; i++) sacc[rt][ct][i] *= 0.125f;  // 1/sqrt(64)
#pragma unroll
  for (int rt = 0; rt < NT; rt++)
#pragma unroll
    for (int i = 0; i < 4; i++) {
      float m = sacc[rt][0][i];
#pragma unroll
      for (int ct = 1; ct < NT; ct++) m = fmaxf(m, sacc[rt][ct][i]);
      for (int off = 1; off < 16; off <<= 1) m = fmaxf(m, __shfl_xor(m, off, 64));
      float ssum = 0.f;
#pragma unroll
      for (int ct = 0; ct < NT; ct++) {
        float p = __expf(sacc[rt][ct][i] - m);
        sacc[rt][ct][i] = p;
        ssum += p;
      }
      for (int off = 1; off < 16; off <<= 1) ssum += __shfl_xor(ssum, off, 64);
      float inv = 1.0f / ssum;
#pragma unroll
      for (int ct = 0; ct < NT; ct++) sacc[rt][ct][i] *= inv;
    }

  // P -> per-wave sP (A-operand bounce); wave-private, compiler handles hazard
#pragma unroll
  for (int rt = 0; rt < NT; rt++)
#pragma unroll
    for (int ct = 0; ct < NT; ct++)
#pragma unroll
      for (int i = 0; i < 4; i++)
        sP[(rt * 16 + q * 4 + i) * PR + ct * 16 + cl] = f2bf(sacc[rt][ct][i]);

  // P fragments: lane (cl,q) of frag mt = rows mt*16+cl, toks q*8..+7
  bf16x8 pf[NT];
#pragma unroll
  for (int mt = 0; mt < NT; mt++) {
    if (L == 32 || q < 2) {
      pf[mt] = ld_frag(sP + (mt * 16 + cl) * PR + q * 8);
    } else {
      union { i4 i; bf16x8 b; } u;
      u.i[0] = u.i[1] = u.i[2] = u.i[3] = 0;
      pf[mt] = u.b;
    }
  }

  // O = P V
  f4 oacc[NT][4];
  { f4 z; z[0]=z[1]=z[2]=z[3]=0.f;
    for (int a = 0; a < NT; a++) for (int b2 = 0; b2 < 4; b2++) oacc[a][b2] = z; }
#pragma unroll
  for (int mt = 0; mt < NT; mt++)
#pragma unroll
    for (int nt = 0; nt < 4; nt++)
      oacc[mt][nt] = mfma_bf16(pf[mt], vf[nt], oacc[mt][nt]);

#pragma unroll
  for (int mt = 0; mt < NT; mt++)
#pragma unroll
    for (int i = 0; i < 4; i++) {
      int r = mt * 16 + q * 4 + i;  // token within group
      u16* dst = Oc + (tok0 + (long)r * tstride) * 1536 + obase + head * 64;
#pragma unroll
      for (int nt = 0; nt < 4; nt++) dst[nt * 16 + cl] = f2bf(oacc[mt][nt][i]);
    }
}

extern "C" void kernel_launch(void* const* d_in, const int* in_sizes, int n_in,
                              void* d_out, int out_size, void* d_ws, size_t ws_size,
                              hipStream_t stream) {
  (void)in_sizes; (void)n_in; (void)out_size; (void)ws_size;
  const float* x    = (const float*)d_in[0];
  const float* wq_w = (const float*)d_in[1];
  const float* wk_w = (const float*)d_in[2];
  const float* wv_w = (const float*)d_in[3];
  const float* wo_w = (const float*)d_in[4];
  const float* bo_w = (const float*)d_in[5];
  const float* wq_h = (const float*)d_in[6];
  const float* wk_h = (const float*)d_in[7];
  const float* wv_h = (const float*)d_in[8];
  const float* wo_h = (const float*)d_in[9];
  const float* bo_h = (const float*)d_in[10];
  const float* wq_t = (const float*)d_in[11];
  const float* wk_t = (const float*)d_in[12];
  const float* wv_t = (const float*)d_in[13];
  const float* wo_t = (const float*)d_in[14];
  const float* bo_t = (const float*)d_in[15];

  char* ws = (char*)d_ws;
  u16* xt    = (u16*)(ws);                 //  64 MiB  (65536 x 512 bf16)
  u16* qkv   = (u16*)(ws + 67108864L);     // 192 MiB  (65536 x 1536 bf16, per-branch)
  u16* oc    = (u16*)(ws + 268435456L);    // 192 MiB  (65536 x 1536 bf16 concat)
  u16* Wqkv  = (u16*)(ws + 469762048L);    // 4.5 MiB
  u16* WoCat = (u16*)(ws + 474480640L);    // 1.5 MiB
  float* bo  = (float*)(ws + 476053504L);  // 2 KiB

  k_transpose_x<<<dim3(512, 16, 4), 256, 0, stream>>>(x, xt);
  k_prep_w<<<dim3(12290), 256, 0, stream>>>(wq_w, wk_w, wv_w, wo_w, bo_w,
                                            wq_h, wk_h, wv_h, wo_h, bo_h,
                                            wq_t, wk_t, wv_t, wo_t, bo_t,
                                            Wqkv, WoCat, bo);
  for (int a = 0; a < 3; a++) {
    // QKV projection for branch a: (65536x512) @ (1536x512)^T -> (65536x1536) bf16
    // NK=8 K-tiles (K=512), NT=6, MT=256, m-major swizzle (A-panel L2 reuse)
    k_gemm256<8, 0, 6, 256, false><<<dim3(1536), 512, 0, stream>>>(
        xt, Wqkv + (long)a * 1536 * 512, qkv, nullptr, 1536);
    if (a == 0)        // width:  tok0 = g*32, stride 1
      k_attn<32><<<dim3(2048, 2), 256, 0, stream>>>(qkv, oc, 1, 0, 32, 0, 1);
    else if (a == 1)   // height: tok0 = (g/32)*1024 + g%32, stride 32
      k_attn<32><<<dim3(2048, 2), 256, 0, stream>>>(qkv, oc, 32, 1, 1024, 512, 32);
    else               // time:   tok0 = (g/1024)*16384 + g%1024, stride 1024, L=16
      k_attn<16><<<dim3(4096, 2), 256, 0, stream>>>(qkv, oc, 1024, 1, 16384, 1024, 1024);
  }
  // Out^T = WoCat(512x1536) @ oc(65536x1536)^T, +bias, scatter to (B,C,T,H,W) f32
  // NK=24 K-tiles (K=1536), NT=256, MT=2, m-minor swizzle (oc L2 pairing)
  k_gemm256<24, 1, 256, 2, true><<<dim3(512), 512, 0, stream>>>(
      WoCat, oc, (float*)d_out, bo, 0);
}